// Round 9
// baseline (2003.471 us; speedup 1.0000x reference)
//
#include <hip/hip_runtime.h>
#include <hip/hip_bf16.h>

#define VOCAB 10000
#define HID   1024
#define OUTN  10000
#define BATCH 32
#define SEQT  256
#define NPAD  10112   // 79*128

typedef short s16x8 __attribute__((ext_vector_type(8)));
typedef float f32x4 __attribute__((ext_vector_type(4)));

#define GLOAD_LDS16(gptr, lptr)                                                      \
  __builtin_amdgcn_global_load_lds((__attribute__((address_space(1))) void*)(gptr),  \
                                   (__attribute__((address_space(3))) void*)(lptr),  \
                                   16, 0, 0)

// NOTE gfx950 operand order: offset:imm must precede sc0/sc1 cache flags.
#define ALOAD16_SC(dst, base, off)                                                   \
  asm volatile("global_load_dwordx4 %0, %1, off offset:%2 sc0 sc1"                   \
               : "=v"(dst) : "v"(base), "n"(off) : "memory")

// ---------------------------------------------------------------- transpose+cast
// src [K][N] f32 row-major  ->  dst [Npad][K] bf16 (rows n>=N zero-filled)
__global__ __launch_bounds__(256) void transpose_cast(
    const float* __restrict__ src, __hip_bfloat16* __restrict__ dst,
    int K, int N, int Npad) {
  __shared__ float tile[32][33];
  const int n0 = blockIdx.x * 32, k0 = blockIdx.y * 32;
  const int tx = threadIdx.x & 31, ty = threadIdx.x >> 5;  // 32 x 8
#pragma unroll
  for (int yy = 0; yy < 32; yy += 8) {
    const int k = k0 + ty + yy, n = n0 + tx;
    tile[ty + yy][tx] = (k < K && n < N) ? src[k * N + n] : 0.f;
  }
  __syncthreads();
#pragma unroll
  for (int yy = 0; yy < 32; yy += 8) {
    const int n = n0 + ty + yy, k = k0 + tx;
    if (n < Npad && k < K) dst[(size_t)n * K + k] = __float2bfloat16(tile[tx][ty + yy]);
  }
}

// also zero-inits the barrier counter each launch (replay-safe, device-scope)
__global__ __launch_bounds__(256) void cast_state(
    const float* __restrict__ s, __hip_bfloat16* __restrict__ d, int n,
    unsigned* __restrict__ counter) {
  const int i = blockIdx.x * 256 + threadIdx.x;
  if (i == 0) atomicExch(counter, 0u);
  if (i < n) d[i] = __float2bfloat16(s[i]);
}

// ---------------------------------------------------------------- persistent recurrence
// Round-4 protocol verbatim (passed, absmax 2.44e-4) + ONE delta: the WG's
// WhhT slice lives in LDS (64 KB, staged once, XOR-swizzled) instead of being
// re-fetched from L2 each step. No asm-held long-lived registers => no
// spill-races-async-load hazard (the rounds 6-8 bug). VGPR ~190.
__global__ __launch_bounds__(256, 1) void rnn_persist(
    __hip_bfloat16* __restrict__ Hbf,          // 257 slots of [32][1024] bf16
    const int* __restrict__ ids,               // [BATCH][SEQT]
    const float* __restrict__ W_xh,            // [VOCAB][HID] f32
    const __hip_bfloat16* __restrict__ WhhT,   // [HID][HID] bf16, [n][k]
    const float* __restrict__ b_h,
    float* __restrict__ Hfin,                  // [32][1024] f32 (tail of d_out)
    unsigned* __restrict__ counter) {
  // [32 cols][1024 k] bf16, 16B chunks XOR-swizzled: chunk c16 of col stored at
  // sw = (c16&~7) | ((c16&7) ^ (col&7))  (bijective per col; spreads the
  // 16-lane same-k column read across 8 bank groups)
  __shared__ __align__(16) __hip_bfloat16 whh[32 * HID];   // 64 KB

  const int wg   = blockIdx.x;
  const int wave = threadIdx.x >> 6;
  const int lane = threadIdx.x & 63;
  const int wm = wave >> 1, wn = wave & 1;
  const int row0 = wm * 16;
  const int col0 = wg * 32 + wn * 16;
  const int l16 = lane & 15;
  const int g   = lane >> 4;                   // 0..3

  // ---- stage WhhT slice -> LDS (coalesced 16B loads, swizzled dest)
  for (int ci = threadIdx.x; ci < 32 * (HID / 8); ci += 256) {
    const int col = ci >> 7;                   // 0..31 (128 chunks per col)
    const int c16 = ci & 127;
    const s16x8 v = *reinterpret_cast<const s16x8*>(
        WhhT + (size_t)(wg * 32 + col) * HID + c16 * 8);
    const int sw = (c16 & ~7) | ((c16 & 7) ^ (col & 7));
    *reinterpret_cast<s16x8*>(reinterpret_cast<char*>(whh) + col * 2048 + sw * 16) = v;
  }

  // C/D layout: col = lane&15, row = (lane>>4)*4 + j   [m89]
  const int ccol  = col0 + l16;
  const int crow0 = row0 + g * 4;
  const float bh = b_h[ccol];

  // ---- prefetch W_xh gather for t=0 (plain cached loads, round-4 verbatim)
  float wxh[4];
#pragma unroll
  for (int j = 0; j < 4; ++j)
    wxh[j] = W_xh[(size_t)ids[(crow0 + j) * SEQT + 0] * HID + ccol];

  __syncthreads();   // whh staged

  const int aOff = (row0 + l16) * HID + g * 8;
  // per-lane LDS read bases (loop-invariant): frag kk even/odd
  const char* myB = reinterpret_cast<const char*>(whh) + (wn * 16 + l16) * 2048;
  const int xorv = l16 & 7;
  const int offE = (g ^ xorv) * 16;            // kk even: c16 = g + 4kk
  const int offO = ((g + 4) ^ xorv) * 16;      // kk odd:  c16 = g + 4kk

  for (int t = 0; t < SEQT; ++t) {
    const __hip_bfloat16* aBase = Hbf + (size_t)t * (BATCH * HID) + aOff;
    __hip_bfloat16* Hnext = Hbf + (size_t)(t + 1) * (BATCH * HID);

    // issue all 32 A loads (device-scope; one latency + drain), then consume
    s16x8 areg[32];
#pragma unroll
    for (int kk = 0; kk < 32; ++kk) ALOAD16_SC(areg[kk], aBase, kk * 64);
    asm volatile("s_waitcnt vmcnt(0)" ::: "memory");
    __builtin_amdgcn_sched_barrier(0);

    f32x4 acc0 = {0.f, 0.f, 0.f, 0.f}, acc1 = {0.f, 0.f, 0.f, 0.f};
#pragma unroll
    for (int kk = 0; kk < 32; kk += 2) {
      const s16x8 b0 = *reinterpret_cast<const s16x8*>(myB + (kk >> 1) * 128 + offE);
      const s16x8 b1 = *reinterpret_cast<const s16x8*>(myB + (kk >> 1) * 128 + offO);
      acc0 = __builtin_amdgcn_mfma_f32_16x16x32_bf16(areg[kk],     b0, acc0, 0, 0, 0);
      acc1 = __builtin_amdgcn_mfma_f32_16x16x32_bf16(areg[kk + 1], b1, acc1, 0, 0, 0);
    }

    // tanh + coherent H store (round-4 verbatim)
#pragma unroll
    for (int j = 0; j < 4; ++j) {
      const float x = acc0[j] + acc1[j] + wxh[j] + bh;
      const float e = __expf(2.f * x);            // tanh = 1 - 2/(e^{2x}+1)
      const float v = 1.f - 2.f / (e + 1.f);
      const __hip_bfloat16 hv = __float2bfloat16(v);
      const unsigned u = *reinterpret_cast<const unsigned short*>(&hv);
      asm volatile("global_store_short %0, %1, off sc0 sc1"
                   :: "v"(Hnext + (crow0 + j) * HID + ccol), "v"(u) : "memory");
      if (t == SEQT - 1) Hfin[(crow0 + j) * HID + ccol] = v;
    }

    // prefetch next step's W_xh gather (round-4 placement: before the sync)
    if (t + 1 < SEQT) {
#pragma unroll
      for (int j = 0; j < 4; ++j)
        wxh[j] = W_xh[(size_t)ids[(crow0 + j) * SEQT + (t + 1)] * HID + ccol];
    }

    if (t + 1 < SEQT) {
      // round-4 verbatim sync: drain -> rendezvous -> atomic bump -> t0 spin
      asm volatile("s_waitcnt vmcnt(0)" ::: "memory");
      __syncthreads();
      if (threadIdx.x == 0) {
        atomicAdd(counter, 1u);                       // device-scope
        const unsigned target = 32u * (unsigned)(t + 1);
        unsigned v;
        do {
          asm volatile("global_load_dword %0, %1, off sc0 sc1\n\t"
                       "s_waitcnt vmcnt(0)"
                       : "=v"(v) : "v"(counter) : "memory");
        } while (v < target);
      }
      __syncthreads();
    }
  }
}

// ---------------------------------------------------------------- output GEMM
// Y[r][n] = sum_k A[r][k]*BT[n][k] + b_q[n]; A=[8192][1024], BT=[10112][1024]
// 128x128 tile, BK=64, 4 waves (2x2, 64x64 each, 4x4 frags of 16x16)
__global__ __launch_bounds__(256) void gemm_out(
    const __hip_bfloat16* __restrict__ A,
    const __hip_bfloat16* __restrict__ BT,
    const float* __restrict__ b_q,
    float* __restrict__ Y) {
  __shared__ __align__(16) __hip_bfloat16 As[128 * 64];
  __shared__ __align__(16) __hip_bfloat16 Bs[128 * 64];

  const int bx = blockIdx.x;   // n tile 0..78
  const int by = blockIdx.y;   // m tile 0..63
  const int wave = threadIdx.x >> 6;
  const int lane = threadIdx.x & 63;
  const int wm = wave >> 1, wn = wave & 1;
  const int l16 = lane & 15;

  const size_t aRow0 = (size_t)by * 128;
  const size_t bRow0 = (size_t)bx * 128;

  f32x4 acc[4][4];
#pragma unroll
  for (int m = 0; m < 4; ++m)
#pragma unroll
    for (int n = 0; n < 4; ++n) acc[m][n] = (f32x4){0.f, 0.f, 0.f, 0.f};

  for (int kt = 0; kt < HID / 64; ++kt) {
    __syncthreads();
    // stage: LDS linear dest, inverse-swizzled global source (rule 21)
#pragma unroll
    for (int q = 0; q < 4; ++q) {
      const int ci = q * 256 + wave * 64 + lane;   // chunk 0..1023 (16B each)
      const int r  = ci >> 3;                      // tile row 0..127
      const int gc = (ci & 7) ^ (r & 7);           // swizzled source chunk
      const __hip_bfloat16* ga = A  + (aRow0 + r) * HID + kt * 64 + gc * 8;
      const __hip_bfloat16* gb = BT + (bRow0 + r) * HID + kt * 64 + gc * 8;
      GLOAD_LDS16(ga, &As[(q * 256 + wave * 64) * 8]);
      GLOAD_LDS16(gb, &Bs[(q * 256 + wave * 64) * 8]);
    }
    __syncthreads();

    s16x8 af[2][4], bf[2][4];
#pragma unroll
    for (int kc = 0; kc < 2; ++kc) {
      const int cc = kc * 4 + (lane >> 4);
#pragma unroll
      for (int m = 0; m < 4; ++m) {
        const int rowA = wm * 64 + m * 16 + l16;
        af[kc][m] = *reinterpret_cast<const s16x8*>(&As[rowA * 64 + ((cc ^ (rowA & 7)) * 8)]);
      }
#pragma unroll
      for (int n = 0; n < 4; ++n) {
        const int rowB = wn * 64 + n * 16 + l16;
        bf[kc][n] = *reinterpret_cast<const s16x8*>(&Bs[rowB * 64 + ((cc ^ (rowB & 7)) * 8)]);
      }
    }
#pragma unroll
    for (int kc = 0; kc < 2; ++kc)
#pragma unroll
      for (int m = 0; m < 4; ++m)
#pragma unroll
        for (int n = 0; n < 4; ++n)
          acc[m][n] = __builtin_amdgcn_mfma_f32_16x16x32_bf16(af[kc][m], bf[kc][n], acc[m][n], 0, 0, 0);
  }

  const int crow0 = by * 128 + wm * 64 + (lane >> 4) * 4;
  const int ccol0 = bx * 128 + wn * 64 + l16;
#pragma unroll
  for (int n = 0; n < 4; ++n) {
    const int ccol = ccol0 + n * 16;
    if (ccol < OUTN) {
      const float bq = b_q[ccol];
#pragma unroll
      for (int m = 0; m < 4; ++m) {
        const int crow = crow0 + m * 16;
#pragma unroll
        for (int j = 0; j < 4; ++j)
          Y[(size_t)(crow + j) * OUTN + ccol] = acc[m][n][j] + bq;
      }
    }
  }
}

// ---------------------------------------------------------------- launch
extern "C" void kernel_launch(void* const* d_in, const int* in_sizes, int n_in,
                              void* d_out, int out_size, void* d_ws, size_t ws_size,
                              hipStream_t stream) {
  const int*   inputs = (const int*)d_in[0];
  const float* state  = (const float*)d_in[1];
  const float* W_xh   = (const float*)d_in[2];
  const float* W_hh   = (const float*)d_in[3];
  const float* b_h    = (const float*)d_in[4];
  const float* W_hq   = (const float*)d_in[5];
  const float* b_q    = (const float*)d_in[6];

  float* Y    = (float*)d_out;                        // [8192][10000]
  float* Hfin = Y + (size_t)SEQT * BATCH * OUTN;      // [32][1024]

  char* ws = (char*)d_ws;
  // Hbf: 257 slots of [32][1024] bf16; slot 0 = state, slot t+1 = H_t
  __hip_bfloat16* Hbf  = (__hip_bfloat16*)ws;                                   // 16,842,752 B
  __hip_bfloat16* WhhT = (__hip_bfloat16*)(ws + 16842752);                      //  2,097,152 B
  __hip_bfloat16* WhqT = (__hip_bfloat16*)(ws + 16842752 + 2097152);            // 20,709,376 B
  // barrier counter: last 128 B of WhqT's zero-pad rows (row 10111 >= OUTN --
  // feeds only discarded GEMM columns). Zeroed by transpose_cast's pad-fill
  // AND by cast_state (round-4-proven placement).
  unsigned* counter    = (unsigned*)(ws + 16842752 + 2097152 + 20709376 - 128);

  transpose_cast<<<dim3(32, 32), 256, 0, stream>>>(W_hh, WhhT, HID, HID, HID);
  transpose_cast<<<dim3(NPAD / 32, 32), 256, 0, stream>>>(W_hq, WhqT, HID, OUTN, NPAD);
  cast_state<<<dim3(BATCH * HID / 256), 256, 0, stream>>>(state, Hbf, BATCH * HID, counter);

  rnn_persist<<<dim3(32), dim3(256), 0, stream>>>(
      Hbf, inputs, W_xh, WhhT, b_h, Hfin, counter);

  // A rows r = t*32+b  <->  Hbf slot t+1 row b  ==  Hbf + (r+32)*1024
  gemm_out<<<dim3(NPAD / 128, 8192 / 128), 256, 0, stream>>>(Hbf + BATCH * HID, WhqT, b_q, Y);
}

// Round 10
// 1906.258 us; speedup vs baseline: 1.0510x; 1.0510x over previous
//
#include <hip/hip_runtime.h>
#include <hip/hip_bf16.h>

#define VOCAB 10000
#define HID   1024
#define OUTN  10000
#define BATCH 32
#define SEQT  256
#define NPAD  10112   // 79*128

typedef short s16x8 __attribute__((ext_vector_type(8)));
typedef float f32x4 __attribute__((ext_vector_type(4)));

#define GLOAD_LDS16(gptr, lptr)                                                      \
  __builtin_amdgcn_global_load_lds((__attribute__((address_space(1))) void*)(gptr),  \
                                   (__attribute__((address_space(3))) void*)(lptr),  \
                                   16, 0, 0)

// NOTE gfx950 operand order: offset:imm must precede sc0/sc1 cache flags.
#define ALOAD16_SC(dst, base, off)                                                   \
  asm volatile("global_load_dwordx4 %0, %1, off offset:%2 sc0 sc1"                   \
               : "=v"(dst) : "v"(base), "n"(off) : "memory")

// ---------------------------------------------------------------- transpose+cast
// src [K][N] f32 row-major  ->  dst [Npad][K] bf16 (rows n>=N zero-filled).
// The zero pad rows also serve as the zeroed flag region for rnn_persist.
__global__ __launch_bounds__(256) void transpose_cast(
    const float* __restrict__ src, __hip_bfloat16* __restrict__ dst,
    int K, int N, int Npad) {
  __shared__ float tile[32][33];
  const int n0 = blockIdx.x * 32, k0 = blockIdx.y * 32;
  const int tx = threadIdx.x & 31, ty = threadIdx.x >> 5;  // 32 x 8
#pragma unroll
  for (int yy = 0; yy < 32; yy += 8) {
    const int k = k0 + ty + yy, n = n0 + tx;
    tile[ty + yy][tx] = (k < K && n < N) ? src[k * N + n] : 0.f;
  }
  __syncthreads();
#pragma unroll
  for (int yy = 0; yy < 32; yy += 8) {
    const int n = n0 + ty + yy, k = k0 + tx;
    if (n < Npad && k < K) dst[(size_t)n * K + k] = __float2bfloat16(tile[tx][ty + yy]);
  }
}

__global__ __launch_bounds__(256) void cast_state(
    const float* __restrict__ s, __hip_bfloat16* __restrict__ d, int n) {
  const int i = blockIdx.x * 256 + threadIdx.x;
  if (i < n) d[i] = __float2bfloat16(s[i]);
}

// ---------------------------------------------------------------- persistent recurrence
// r9 compute path verbatim (passed, absmax 2.44e-4) + sync-path changes:
//   release: per-WG flag line (128B apart) via atomicExch after store drain
//   acquire: ALL-lane spin (lane l polls flags[l&31]), no trailing barrier
//   wxh prefetch moved AFTER the release (off the critical path)
__global__ __launch_bounds__(256, 1) void rnn_persist(
    __hip_bfloat16* __restrict__ Hbf,          // 257 slots of [32][1024] bf16
    const int* __restrict__ ids,               // [BATCH][SEQT]
    const float* __restrict__ W_xh,            // [VOCAB][HID] f32
    const __hip_bfloat16* __restrict__ WhhT,   // [HID][HID] bf16, [n][k]
    const float* __restrict__ b_h,
    float* __restrict__ Hfin,                  // [32][1024] f32 (tail of d_out)
    unsigned* __restrict__ flags) {            // 32 flags, stride 32 dwords (128B)
  // [32 cols][1024 k] bf16, 16B chunks XOR-swizzled: chunk c16 of col stored at
  // sw = (c16&~7) | ((c16&7) ^ (col&7))
  __shared__ __align__(16) __hip_bfloat16 whh[32 * HID];   // 64 KB

  const int wg   = blockIdx.x;
  const int wave = threadIdx.x >> 6;
  const int lane = threadIdx.x & 63;
  const int wm = wave >> 1, wn = wave & 1;
  const int row0 = wm * 16;
  const int col0 = wg * 32 + wn * 16;
  const int l16 = lane & 15;
  const int g   = lane >> 4;                   // 0..3

  // ---- stage WhhT slice -> LDS (coalesced 16B loads, swizzled dest)
  for (int ci = threadIdx.x; ci < 32 * (HID / 8); ci += 256) {
    const int col = ci >> 7;                   // 0..31 (128 chunks per col)
    const int c16 = ci & 127;
    const s16x8 v = *reinterpret_cast<const s16x8*>(
        WhhT + (size_t)(wg * 32 + col) * HID + c16 * 8);
    const int sw = (c16 & ~7) | ((c16 & 7) ^ (col & 7));
    *reinterpret_cast<s16x8*>(reinterpret_cast<char*>(whh) + col * 2048 + sw * 16) = v;
  }

  // C/D layout: col = lane&15, row = (lane>>4)*4 + j   [m89]
  const int ccol  = col0 + l16;
  const int crow0 = row0 + g * 4;
  const float bh = b_h[ccol];

  // ---- prefetch W_xh gather for t=0
  float wxh[4];
#pragma unroll
  for (int j = 0; j < 4; ++j)
    wxh[j] = W_xh[(size_t)ids[(crow0 + j) * SEQT + 0] * HID + ccol];

  __syncthreads();   // whh staged

  const int aOff = (row0 + l16) * HID + g * 8;
  // per-lane LDS read bases (loop-invariant): frag kk even/odd
  const char* myB = reinterpret_cast<const char*>(whh) + (wn * 16 + l16) * 2048;
  const int xorv = l16 & 7;
  const int offE = (g ^ xorv) * 16;            // kk even: c16 = g + 4kk
  const int offO = ((g + 4) ^ xorv) * 16;      // kk odd:  c16 = g + 4kk

  for (int t = 0; t < SEQT; ++t) {
    const __hip_bfloat16* aBase = Hbf + (size_t)t * (BATCH * HID) + aOff;
    __hip_bfloat16* Hnext = Hbf + (size_t)(t + 1) * (BATCH * HID);

    // issue all 32 A loads (device-scope; one latency + drain), then consume
    s16x8 areg[32];
#pragma unroll
    for (int kk = 0; kk < 32; ++kk) ALOAD16_SC(areg[kk], aBase, kk * 64);
    asm volatile("s_waitcnt vmcnt(0)" ::: "memory");
    __builtin_amdgcn_sched_barrier(0);

    f32x4 acc0 = {0.f, 0.f, 0.f, 0.f}, acc1 = {0.f, 0.f, 0.f, 0.f};
#pragma unroll
    for (int kk = 0; kk < 32; kk += 2) {
      const s16x8 b0 = *reinterpret_cast<const s16x8*>(myB + (kk >> 1) * 128 + offE);
      const s16x8 b1 = *reinterpret_cast<const s16x8*>(myB + (kk >> 1) * 128 + offO);
      acc0 = __builtin_amdgcn_mfma_f32_16x16x32_bf16(areg[kk],     b0, acc0, 0, 0, 0);
      acc1 = __builtin_amdgcn_mfma_f32_16x16x32_bf16(areg[kk + 1], b1, acc1, 0, 0, 0);
    }

    // tanh + coherent H store
#pragma unroll
    for (int j = 0; j < 4; ++j) {
      const float x = acc0[j] + acc1[j] + wxh[j] + bh;
      const float e = __expf(2.f * x);            // tanh = 1 - 2/(e^{2x}+1)
      const float v = 1.f - 2.f / (e + 1.f);
      const __hip_bfloat16 hv = __float2bfloat16(v);
      const unsigned u = *reinterpret_cast<const unsigned short*>(&hv);
      asm volatile("global_store_short %0, %1, off sc0 sc1"
                   :: "v"(Hnext + (crow0 + j) * HID + ccol), "v"(u) : "memory");
      if (t == SEQT - 1) Hfin[(crow0 + j) * HID + ccol] = v;
    }

    if (t + 1 < SEQT) {
      // release: drain own H stores -> WG rendezvous -> per-WG flag atomic
      asm volatile("s_waitcnt vmcnt(0)" ::: "memory");
      __syncthreads();
      if (threadIdx.x == 0) atomicExch(flags + wg * 32, (unsigned)(t + 1));

      // prefetch next step's W_xh gather AFTER the release (overlaps the spin;
      // the spin's vmcnt(0) drains it; compiler waits before use at next tanh)
#pragma unroll
      for (int j = 0; j < 4; ++j)
        wxh[j] = W_xh[(size_t)ids[(crow0 + j) * SEQT + (t + 1)] * HID + ccol];

      // acquire: all waves spin; lane l watches flags[l&31]; each wave exits
      // on its own observation of all 32 flags >= t+1 (no trailing barrier)
      const unsigned* myflag = flags + (lane & 31) * 32;
      const unsigned target = (unsigned)(t + 1);
      unsigned f;
      do {
        asm volatile("global_load_dword %0, %1, off sc0 sc1\n\t"
                     "s_waitcnt vmcnt(0)"
                     : "=v"(f) : "v"(myflag) : "memory");
      } while (__all((int)(f >= target)) == 0);
      __builtin_amdgcn_sched_barrier(0);
    }
  }
}

// ---------------------------------------------------------------- output GEMM
// Y[r][n] = sum_k A[r][k]*BT[n][k] + b_q[n]; A=[8192][1024], BT=[10112][1024]
// 128x128 tile, BK=64, 4 waves (2x2, 64x64 each, 4x4 frags of 16x16)
__global__ __launch_bounds__(256) void gemm_out(
    const __hip_bfloat16* __restrict__ A,
    const __hip_bfloat16* __restrict__ BT,
    const float* __restrict__ b_q,
    float* __restrict__ Y) {
  __shared__ __align__(16) __hip_bfloat16 As[128 * 64];
  __shared__ __align__(16) __hip_bfloat16 Bs[128 * 64];

  const int bx = blockIdx.x;   // n tile 0..78
  const int by = blockIdx.y;   // m tile 0..63
  const int wave = threadIdx.x >> 6;
  const int lane = threadIdx.x & 63;
  const int wm = wave >> 1, wn = wave & 1;
  const int l16 = lane & 15;

  const size_t aRow0 = (size_t)by * 128;
  const size_t bRow0 = (size_t)bx * 128;

  f32x4 acc[4][4];
#pragma unroll
  for (int m = 0; m < 4; ++m)
#pragma unroll
    for (int n = 0; n < 4; ++n) acc[m][n] = (f32x4){0.f, 0.f, 0.f, 0.f};

  for (int kt = 0; kt < HID / 64; ++kt) {
    __syncthreads();
    // stage: LDS linear dest, inverse-swizzled global source (rule 21)
#pragma unroll
    for (int q = 0; q < 4; ++q) {
      const int ci = q * 256 + wave * 64 + lane;   // chunk 0..1023 (16B each)
      const int r  = ci >> 3;                      // tile row 0..127
      const int gc = (ci & 7) ^ (r & 7);           // swizzled source chunk
      const __hip_bfloat16* ga = A  + (aRow0 + r) * HID + kt * 64 + gc * 8;
      const __hip_bfloat16* gb = BT + (bRow0 + r) * HID + kt * 64 + gc * 8;
      GLOAD_LDS16(ga, &As[(q * 256 + wave * 64) * 8]);
      GLOAD_LDS16(gb, &Bs[(q * 256 + wave * 64) * 8]);
    }
    __syncthreads();

    s16x8 af[2][4], bf[2][4];
#pragma unroll
    for (int kc = 0; kc < 2; ++kc) {
      const int cc = kc * 4 + (lane >> 4);
#pragma unroll
      for (int m = 0; m < 4; ++m) {
        const int rowA = wm * 64 + m * 16 + l16;
        af[kc][m] = *reinterpret_cast<const s16x8*>(&As[rowA * 64 + ((cc ^ (rowA & 7)) * 8)]);
      }
#pragma unroll
      for (int n = 0; n < 4; ++n) {
        const int rowB = wn * 64 + n * 16 + l16;
        bf[kc][n] = *reinterpret_cast<const s16x8*>(&Bs[rowB * 64 + ((cc ^ (rowB & 7)) * 8)]);
      }
    }
#pragma unroll
    for (int kc = 0; kc < 2; ++kc)
#pragma unroll
      for (int m = 0; m < 4; ++m)
#pragma unroll
        for (int n = 0; n < 4; ++n)
          acc[m][n] = __builtin_amdgcn_mfma_f32_16x16x32_bf16(af[kc][m], bf[kc][n], acc[m][n], 0, 0, 0);
  }

  const int crow0 = by * 128 + wm * 64 + (lane >> 4) * 4;
  const int ccol0 = bx * 128 + wn * 64 + l16;
#pragma unroll
  for (int n = 0; n < 4; ++n) {
    const int ccol = ccol0 + n * 16;
    if (ccol < OUTN) {
      const float bq = b_q[ccol];
#pragma unroll
      for (int m = 0; m < 4; ++m) {
        const int crow = crow0 + m * 16;
#pragma unroll
        for (int j = 0; j < 4; ++j)
          Y[(size_t)(crow + j) * OUTN + ccol] = acc[m][n][j] + bq;
      }
    }
  }
}

// ---------------------------------------------------------------- launch
extern "C" void kernel_launch(void* const* d_in, const int* in_sizes, int n_in,
                              void* d_out, int out_size, void* d_ws, size_t ws_size,
                              hipStream_t stream) {
  const int*   inputs = (const int*)d_in[0];
  const float* state  = (const float*)d_in[1];
  const float* W_xh   = (const float*)d_in[2];
  const float* W_hh   = (const float*)d_in[3];
  const float* b_h    = (const float*)d_in[4];
  const float* W_hq   = (const float*)d_in[5];
  const float* b_q    = (const float*)d_in[6];

  float* Y    = (float*)d_out;                        // [8192][10000]
  float* Hfin = Y + (size_t)SEQT * BATCH * OUTN;      // [32][1024]

  char* ws = (char*)d_ws;
  // Hbf: 257 slots of [32][1024] bf16; slot 0 = state, slot t+1 = H_t
  __hip_bfloat16* Hbf  = (__hip_bfloat16*)ws;                                   // 16,842,752 B
  __hip_bfloat16* WhhT = (__hip_bfloat16*)(ws + 16842752);                      //  2,097,152 B
  __hip_bfloat16* WhqT = (__hip_bfloat16*)(ws + 16842752 + 2097152);            // 20,709,376 B
  // flags: last 4 KB of WhqT (pad rows 10110-10111 >= OUTN => only feed
  // discarded GEMM columns; zero-filled by transpose_cast EVERY launch).
  // 32 flags at 128 B stride.
  unsigned* flags      = (unsigned*)(ws + 16842752 + 2097152 + 20709376 - 4096);

  transpose_cast<<<dim3(32, 32), 256, 0, stream>>>(W_hh, WhhT, HID, HID, HID);
  transpose_cast<<<dim3(NPAD / 32, 32), 256, 0, stream>>>(W_hq, WhqT, HID, OUTN, NPAD);
  cast_state<<<dim3(BATCH * HID / 256), 256, 0, stream>>>(state, Hbf, BATCH * HID);

  rnn_persist<<<dim3(32), dim3(256), 0, stream>>>(
      Hbf, inputs, W_xh, WhhT, b_h, Hfin, flags);

  // A rows r = t*32+b  <->  Hbf slot t+1 row b  ==  Hbf + (r+32)*1024
  gemm_out<<<dim3(NPAD / 128, 8192 / 128), 256, 0, stream>>>(Hbf + BATCH * HID, WhqT, b_q, Y);
}

// Round 11
// 1763.712 us; speedup vs baseline: 1.1359x; 1.0808x over previous
//
#include <hip/hip_runtime.h>
#include <hip/hip_bf16.h>

#define VOCAB 10000
#define HID   1024
#define OUTN  10000
#define BATCH 32
#define SEQT  256
#define NPAD  10112   // 79*128

typedef short s16x8 __attribute__((ext_vector_type(8)));
typedef float f32x4 __attribute__((ext_vector_type(4)));
typedef unsigned u32x2 __attribute__((ext_vector_type(2)));

#define GLOAD_LDS16(gptr, lptr)                                                      \
  __builtin_amdgcn_global_load_lds((__attribute__((address_space(1))) void*)(gptr),  \
                                   (__attribute__((address_space(3))) void*)(lptr),  \
                                   16, 0, 0)

// NOTE gfx950 operand order: offset:imm must precede sc0/sc1 cache flags.
#define ALOAD16_SC(dst, base, off)                                                   \
  asm volatile("global_load_dwordx4 %0, %1, off offset:%2 sc0 sc1"                   \
               : "=v"(dst) : "v"(base), "n"(off) : "memory")

__device__ __forceinline__ unsigned bfbits(float f) {
  __hip_bfloat16 h = __float2bfloat16(f);
  return (unsigned)*reinterpret_cast<unsigned short*>(&h);
}

// ---------------------------------------------------------------- transpose+cast
// src [K][N] f32 row-major  ->  dst [Npad][K] bf16 (rows n>=N zero-filled).
// The zero pad rows also serve as the zeroed flag region for rnn_persist.
__global__ __launch_bounds__(256) void transpose_cast(
    const float* __restrict__ src, __hip_bfloat16* __restrict__ dst,
    int K, int N, int Npad) {
  __shared__ float tile[32][33];
  const int n0 = blockIdx.x * 32, k0 = blockIdx.y * 32;
  const int tx = threadIdx.x & 31, ty = threadIdx.x >> 5;  // 32 x 8
#pragma unroll
  for (int yy = 0; yy < 32; yy += 8) {
    const int k = k0 + ty + yy, n = n0 + tx;
    tile[ty + yy][tx] = (k < K && n < N) ? src[k * N + n] : 0.f;
  }
  __syncthreads();
#pragma unroll
  for (int yy = 0; yy < 32; yy += 8) {
    const int n = n0 + ty + yy, k = k0 + tx;
    if (n < Npad && k < K) dst[(size_t)n * K + k] = __float2bfloat16(tile[tx][ty + yy]);
  }
}

__global__ __launch_bounds__(256) void cast_state(
    const float* __restrict__ s, __hip_bfloat16* __restrict__ d, int n) {
  const int i = blockIdx.x * 256 + threadIdx.x;
  if (i < n) d[i] = __float2bfloat16(s[i]);
}

// ---------------------------------------------------------------- persistent recurrence
// R10 structure + operand-swapped MFMA epilogue: compute C^T = mfma(Wfrag,Hfrag)
// so each lane owns 4 CONSECUTIVE out-columns of one batch row =>
//   H store: 1x 8B dwordx2 (was 4x 2B shorts)  -- dword-granular write-through
//   W_xh gather: 1x float4 (was 4x scattered floats)
//   b_h / Hfin: one float4 each
// Numerically bit-identical (same products, same accumulation order).
__global__ __launch_bounds__(256, 1) void rnn_persist(
    __hip_bfloat16* __restrict__ Hbf,          // 257 slots of [32][1024] bf16
    const int* __restrict__ ids,               // [BATCH][SEQT]
    const float* __restrict__ W_xh,            // [VOCAB][HID] f32
    const __hip_bfloat16* __restrict__ WhhT,   // [HID][HID] bf16, [n][k]
    const float* __restrict__ b_h,
    float* __restrict__ Hfin,                  // [32][1024] f32 (tail of d_out)
    unsigned* __restrict__ flags) {            // 32 flags, stride 32 dwords (128B)
  // [32 cols][1024 k] bf16, 16B chunks XOR-swizzled: chunk c16 of col stored at
  // sw = (c16&~7) | ((c16&7) ^ (col&7))
  __shared__ __align__(16) __hip_bfloat16 whh[32 * HID];   // 64 KB

  const int wg   = blockIdx.x;
  const int wave = threadIdx.x >> 6;
  const int lane = threadIdx.x & 63;
  const int wm = wave >> 1, wn = wave & 1;
  const int r0 = wm * 16;                      // batch-row base (16 rows/wave)
  const int c0 = wg * 32 + wn * 16;            // out-col base (16 cols/wave)
  const int l16 = lane & 15;
  const int g   = lane >> 4;                   // 0..3

  // ---- stage WhhT slice -> LDS (coalesced 16B loads, swizzled dest)
  for (int ci = threadIdx.x; ci < 32 * (HID / 8); ci += 256) {
    const int col = ci >> 7;                   // 0..31 (128 chunks per col)
    const int c16 = ci & 127;
    const s16x8 v = *reinterpret_cast<const s16x8*>(
        WhhT + (size_t)(wg * 32 + col) * HID + c16 * 8);
    const int sw = (c16 & ~7) | ((c16 & 7) ^ (col & 7));
    *reinterpret_cast<s16x8*>(reinterpret_cast<char*>(whh) + col * 2048 + sw * 16) = v;
  }

  // swapped C/D layout: C row = outcol = g*4+jj, C col = batch = l16
  const int orow = r0 + l16;                   // this lane's batch row
  const int oc   = c0 + g * 4;                 // first of 4 consecutive out cols
  const f32x4 bh4 = *reinterpret_cast<const f32x4*>(b_h + oc);

  // ---- prefetch W_xh gather for t=0 (one float4 per lane)
  f32x4 wxh4 = *reinterpret_cast<const f32x4*>(
      W_xh + (size_t)ids[orow * SEQT + 0] * HID + oc);

  __syncthreads();   // whh staged

  const int aOff = (r0 + l16) * HID + g * 8;   // H fragment (B-operand now)
  // per-lane LDS read bases (loop-invariant): frag kk even/odd
  const char* myB = reinterpret_cast<const char*>(whh) + (wn * 16 + l16) * 2048;
  const int xorv = l16 & 7;
  const int offE = (g ^ xorv) * 16;            // kk even: c16 = g + 4kk
  const int offO = ((g + 4) ^ xorv) * 16;      // kk odd:  c16 = g + 4kk

  for (int t = 0; t < SEQT; ++t) {
    const __hip_bfloat16* aBase = Hbf + (size_t)t * (BATCH * HID) + aOff;
    __hip_bfloat16* Hnext = Hbf + (size_t)(t + 1) * (BATCH * HID);

    // issue all 32 A loads (device-scope; one latency + drain), then consume
    s16x8 areg[32];
#pragma unroll
    for (int kk = 0; kk < 32; ++kk) ALOAD16_SC(areg[kk], aBase, kk * 64);
    asm volatile("s_waitcnt vmcnt(0)" ::: "memory");
    __builtin_amdgcn_sched_barrier(0);

    f32x4 acc0 = {0.f, 0.f, 0.f, 0.f}, acc1 = {0.f, 0.f, 0.f, 0.f};
#pragma unroll
    for (int kk = 0; kk < 32; kk += 2) {
      const s16x8 b0 = *reinterpret_cast<const s16x8*>(myB + (kk >> 1) * 128 + offE);
      const s16x8 b1 = *reinterpret_cast<const s16x8*>(myB + (kk >> 1) * 128 + offO);
      // SWAPPED operands: A=W-frag, B=H-frag  =>  C^T
      acc0 = __builtin_amdgcn_mfma_f32_16x16x32_bf16(b0, areg[kk],     acc0, 0, 0, 0);
      acc1 = __builtin_amdgcn_mfma_f32_16x16x32_bf16(b1, areg[kk + 1], acc1, 0, 0, 0);
    }

    // tanh + ONE 8B coherent H store (4 consecutive out-cols of one row)
    float x[4];
#pragma unroll
    for (int jj = 0; jj < 4; ++jj) {
      const float s = acc0[jj] + acc1[jj] + wxh4[jj] + bh4[jj];
      const float e = __expf(2.f * s);            // tanh = 1 - 2/(e^{2x}+1)
      x[jj] = 1.f - 2.f / (e + 1.f);
    }
    u32x2 pk;
    pk[0] = bfbits(x[0]) | (bfbits(x[1]) << 16);
    pk[1] = bfbits(x[2]) | (bfbits(x[3]) << 16);
    asm volatile("global_store_dwordx2 %0, %1, off sc0 sc1"
                 :: "v"(Hnext + orow * HID + oc), "v"(pk) : "memory");
    if (t == SEQT - 1)
      *reinterpret_cast<f32x4*>(Hfin + orow * HID + oc) = (f32x4){x[0], x[1], x[2], x[3]};

    if (t + 1 < SEQT) {
      // release: drain own H store -> WG rendezvous -> per-WG flag atomic
      asm volatile("s_waitcnt vmcnt(0)" ::: "memory");
      __syncthreads();
      if (threadIdx.x == 0) atomicExch(flags + wg * 32, (unsigned)(t + 1));

      // prefetch next step's W_xh float4 AFTER the release (overlaps the spin)
      wxh4 = *reinterpret_cast<const f32x4*>(
          W_xh + (size_t)ids[orow * SEQT + (t + 1)] * HID + oc);

      // acquire: all waves spin; lane l watches flags[l&31]
      const unsigned* myflag = flags + (lane & 31) * 32;
      const unsigned target = (unsigned)(t + 1);
      unsigned f;
      do {
        asm volatile("global_load_dword %0, %1, off sc0 sc1\n\t"
                     "s_waitcnt vmcnt(0)"
                     : "=v"(f) : "v"(myflag) : "memory");
      } while (__all((int)(f >= target)) == 0);
      __builtin_amdgcn_sched_barrier(0);
    }
  }
}

// ---------------------------------------------------------------- output GEMM
// Y[r][n] = sum_k A[r][k]*BT[n][k] + b_q[n]; A=[8192][1024], BT=[10112][1024]
// 128x128 tile, BK=64, 4 waves (2x2, 64x64 each, 4x4 frags of 16x16)
__global__ __launch_bounds__(256) void gemm_out(
    const __hip_bfloat16* __restrict__ A,
    const __hip_bfloat16* __restrict__ BT,
    const float* __restrict__ b_q,
    float* __restrict__ Y) {
  __shared__ __align__(16) __hip_bfloat16 As[128 * 64];
  __shared__ __align__(16) __hip_bfloat16 Bs[128 * 64];

  const int bx = blockIdx.x;   // n tile 0..78
  const int by = blockIdx.y;   // m tile 0..63
  const int wave = threadIdx.x >> 6;
  const int lane = threadIdx.x & 63;
  const int wm = wave >> 1, wn = wave & 1;
  const int l16 = lane & 15;

  const size_t aRow0 = (size_t)by * 128;
  const size_t bRow0 = (size_t)bx * 128;

  f32x4 acc[4][4];
#pragma unroll
  for (int m = 0; m < 4; ++m)
#pragma unroll
    for (int n = 0; n < 4; ++n) acc[m][n] = (f32x4){0.f, 0.f, 0.f, 0.f};

  for (int kt = 0; kt < HID / 64; ++kt) {
    __syncthreads();
    // stage: LDS linear dest, inverse-swizzled global source (rule 21)
#pragma unroll
    for (int q = 0; q < 4; ++q) {
      const int ci = q * 256 + wave * 64 + lane;   // chunk 0..1023 (16B each)
      const int r  = ci >> 3;                      // tile row 0..127
      const int gc = (ci & 7) ^ (r & 7);           // swizzled source chunk
      const __hip_bfloat16* ga = A  + (aRow0 + r) * HID + kt * 64 + gc * 8;
      const __hip_bfloat16* gb = BT + (bRow0 + r) * HID + kt * 64 + gc * 8;
      GLOAD_LDS16(ga, &As[(q * 256 + wave * 64) * 8]);
      GLOAD_LDS16(gb, &Bs[(q * 256 + wave * 64) * 8]);
    }
    __syncthreads();

    s16x8 af[2][4], bf[2][4];
#pragma unroll
    for (int kc = 0; kc < 2; ++kc) {
      const int cc = kc * 4 + (lane >> 4);
#pragma unroll
      for (int m = 0; m < 4; ++m) {
        const int rowA = wm * 64 + m * 16 + l16;
        af[kc][m] = *reinterpret_cast<const s16x8*>(&As[rowA * 64 + ((cc ^ (rowA & 7)) * 8)]);
      }
#pragma unroll
      for (int n = 0; n < 4; ++n) {
        const int rowB = wn * 64 + n * 16 + l16;
        bf[kc][n] = *reinterpret_cast<const s16x8*>(&Bs[rowB * 64 + ((cc ^ (rowB & 7)) * 8)]);
      }
    }
#pragma unroll
    for (int kc = 0; kc < 2; ++kc)
#pragma unroll
      for (int m = 0; m < 4; ++m)
#pragma unroll
        for (int n = 0; n < 4; ++n)
          acc[m][n] = __builtin_amdgcn_mfma_f32_16x16x32_bf16(af[kc][m], bf[kc][n], acc[m][n], 0, 0, 0);
  }

  const int crow0 = by * 128 + wm * 64 + (lane >> 4) * 4;
  const int ccol0 = bx * 128 + wn * 64 + l16;
#pragma unroll
  for (int n = 0; n < 4; ++n) {
    const int ccol = ccol0 + n * 16;
    if (ccol < OUTN) {
      const float bq = b_q[ccol];
#pragma unroll
      for (int m = 0; m < 4; ++m) {
        const int crow = crow0 + m * 16;
#pragma unroll
        for (int j = 0; j < 4; ++j)
          Y[(size_t)(crow + j) * OUTN + ccol] = acc[m][n][j] + bq;
      }
    }
  }
}

// ---------------------------------------------------------------- launch
extern "C" void kernel_launch(void* const* d_in, const int* in_sizes, int n_in,
                              void* d_out, int out_size, void* d_ws, size_t ws_size,
                              hipStream_t stream) {
  const int*   inputs = (const int*)d_in[0];
  const float* state  = (const float*)d_in[1];
  const float* W_xh   = (const float*)d_in[2];
  const float* W_hh   = (const float*)d_in[3];
  const float* b_h    = (const float*)d_in[4];
  const float* W_hq   = (const float*)d_in[5];
  const float* b_q    = (const float*)d_in[6];

  float* Y    = (float*)d_out;                        // [8192][10000]
  float* Hfin = Y + (size_t)SEQT * BATCH * OUTN;      // [32][1024]

  char* ws = (char*)d_ws;
  // Hbf: 257 slots of [32][1024] bf16; slot 0 = state, slot t+1 = H_t
  __hip_bfloat16* Hbf  = (__hip_bfloat16*)ws;                                   // 16,842,752 B
  __hip_bfloat16* WhhT = (__hip_bfloat16*)(ws + 16842752);                      //  2,097,152 B
  __hip_bfloat16* WhqT = (__hip_bfloat16*)(ws + 16842752 + 2097152);            // 20,709,376 B
  // flags: last 4 KB of WhqT (pad rows 10110-10111 >= OUTN => only feed
  // discarded GEMM columns; zero-filled by transpose_cast EVERY launch).
  // 32 flags at 128 B stride.
  unsigned* flags      = (unsigned*)(ws + 16842752 + 2097152 + 20709376 - 4096);

  transpose_cast<<<dim3(32, 32), 256, 0, stream>>>(W_hh, WhhT, HID, HID, HID);
  transpose_cast<<<dim3(NPAD / 32, 32), 256, 0, stream>>>(W_hq, WhqT, HID, OUTN, NPAD);
  cast_state<<<dim3(BATCH * HID / 256), 256, 0, stream>>>(state, Hbf, BATCH * HID);

  rnn_persist<<<dim3(32), dim3(256), 0, stream>>>(
      Hbf, inputs, W_xh, WhhT, b_h, Hfin, flags);

  // A rows r = t*32+b  <->  Hbf slot t+1 row b  ==  Hbf + (r+32)*1024
  gemm_out<<<dim3(NPAD / 128, 8192 / 128), 256, 0, stream>>>(Hbf + BATCH * HID, WhqT, b_q, Y);
}